// Round 1
// baseline (76.426 us; speedup 1.0000x reference)
//
#include <hip/hip_runtime.h>

#define NB 8
#define NP 16
#define NV 64
#define ND 1986

// output offsets in floats (concatenated return order)
#define OFF_POINTS 0         // (8,16*1986,3)    762624
#define OFF_DH     762624    // (8,16,1986,4)   1016832
#define OFF_OVER   1779456   // (8,16,1)            128
#define OFF_MEAN   1779584   // (8,16,3)            384
#define OFF_DIRS   1779968   // (1986,3)           5958
#define OFF_LOCALV 1785926   // (8,16,64,3)       24576
// total 1810502

__global__ __launch_bounds__(256, 4) void mcx_kernel(
    const float* __restrict__ verts,    // (8,16,64,3)
    const float* __restrict__ smooth,   // (8,16)
    float* __restrict__ out)
{
    const int t     = threadIdx.x;
    const int bp    = blockIdx.x >> 3;   // 0..127
    const int chunk = blockIdx.x & 7;    // 0..7
    const int d     = chunk * 256 + t;   // direction id

    __shared__ float lv[NV][4];          // padded float4 layout
    __shared__ float mean_sh[3];

    // ---- stage 1: load vertices, compute mean, local_v ----
    const int v3 = t / 3;
    const int c3 = t - v3 * 3;
    if (t < 192) lv[v3][c3] = verts[bp * 192 + t];
    else         lv[t - 192][3] = 0.f;
    __syncthreads();
    if (t < 3) {
        float s = 0.f;
        for (int v = 0; v < NV; ++v) s += lv[v][t];
        mean_sh[t] = s * (1.f / 64.f);
    }
    __syncthreads();
    const float m0 = mean_sh[0], m1 = mean_sh[1], m2 = mean_sh[2];
    if (t < 192) lv[v3][c3] -= mean_sh[c3];
    __syncthreads();

    if (chunk == 0) {
        if (t < 192) out[OFF_LOCALV + bp * 192 + t] = lv[v3][c3];
        if (t < 3)   out[OFF_MEAN + bp * 3 + t] = mean_sh[t];
        if (t == 3)  out[OFF_OVER + bp] = 0.f;
    }

    if (d >= ND) return;

    // ---- stage 2: direction vector (linspace in double, trig in float) ----
    int i, j;
    if (d < 1984) { i = 1 + (d >> 6); j = d & 63; }
    else          { i = (d == 1984) ? 0 : 32; j = 0; }
    const double STEP = 3.141592653589793 / 32.0;  // == pi/32, same step for th1 & th2
    const float th1 = (float)(-1.5707963267948966 + (double)i * STEP);
    const float th2 = (float)(-3.141592653589793  + (double)j * STEP);
    const float c1 = cosf(th1), s1 = sinf(th1);
    const float c2 = cosf(th2), s2 = sinf(th2);
    const float dx = c1 * c2, dy = c1 * s2, dz = s1;
    if (bp == 0) {
        out[OFF_DIRS + d * 3 + 0] = dx;
        out[OFF_DIRS + d * 3 + 1] = dy;
        out[OFF_DIRS + d * 3 + 2] = dz;
    }

    // ---- stage 3: stable p-norm support function ----
    const float sm  = smooth[bp];      // p (wave-uniform)
    const float ip  = 1.0f / sm;
    const float pm1 = sm - 1.0f;

    float zv[NV];
    float zmax = 0.f;                  // max over zm = max(z,0): init 0 handles all-negative
    #pragma unroll
    for (int v = 0; v < NV; ++v) {
        float z = fmaf(lv[v][0], dx, fmaf(lv[v][1], dy, lv[v][2] * dz));
        zv[v] = z;
        zmax = fmaxf(zmax, z);
    }

    // k rescale (replicates reference semantics; zmax==0 -> log10=-inf -> k=1e20)
    const float zlog = log10f(zmax);
    const float expo = zlog * sm;
    const float lk   = (expo < -20.f) ? ((-20.f - expo) / sm) : 0.f;
    const float kc   = fminf(fmaxf(ceilf(lk), 0.f), 20.f);
    const float k    = exp2f(kc * 3.3219280948873623f);  // 10^kc

    // pass 2: sum of clip(zms^p, LB, UB) over positive entries; cache lz=log2(zms)
    float sum = 0.f;
    #pragma unroll
    for (int v = 0; v < NV; ++v) {
        float zms = fmaxf(zv[v], 0.f) * k;
        float lz  = log2f(zms);                 // -inf when zms == 0
        zv[v] = lz;
        float t2 = exp2f(sm * lz);              // zms^p (0 when zms==0)
        t2 = fminf(fmaxf(t2, 1e-20f), 1e20f);
        sum += (zms > 0.f) ? t2 : 0.f;          // non-pos contributes exactly 0
    }

    // h = clip(sum^(1/p), LB, UB)
    const float h  = fminf(fmaxf(exp2f(ip * log2f(sum)), 1e-20f), 1e20f);
    const float lh = log2f(h);

    // pass 3: dhdz = clip((zms/h)^(p-1), LB, UB); lz==-inf gives exp2(-inf)=0 -> clamps to LB
    float sx = 0.f, sy = 0.f, sz = 0.f;
    #pragma unroll
    for (int v = 0; v < NV; ++v) {
        float e  = pm1 * (zv[v] - lh);
        float dh = fminf(fmaxf(exp2f(e), 1e-20f), 1e20f);
        sx = fmaf(dh, lv[v][0], sx);
        sy = fmaf(dh, lv[v][1], sy);
        sz = fmaf(dh, lv[v][2], sz);
    }

    const int idx = bp * ND + d;
    out[OFF_POINTS + idx * 3 + 0] = sx + m0;
    out[OFF_POINTS + idx * 3 + 1] = sy + m1;
    out[OFF_POINTS + idx * 3 + 2] = sz + m2;

    const float hout = fminf(h / k, 1e20f);     // clip(h/k, -UB, UB), h>0
    out[OFF_DH + idx * 4 + 0] = dx;
    out[OFF_DH + idx * 4 + 1] = dy;
    out[OFF_DH + idx * 4 + 2] = dz;
    out[OFF_DH + idx * 4 + 3] = hout;
}

extern "C" void kernel_launch(void* const* d_in, const int* in_sizes, int n_in,
                              void* d_out, int out_size, void* d_ws, size_t ws_size,
                              hipStream_t stream) {
    const float* verts  = (const float*)d_in[0];   // (8,16,64,3) f32
    const float* smooth = (const float*)d_in[1];   // (8,16) f32
    float* out = (float*)d_out;
    (void)d_ws; (void)ws_size; (void)in_sizes; (void)n_in; (void)out_size;
    mcx_kernel<<<dim3(NB * NP * 8), dim3(256), 0, stream>>>(verts, smooth, out);
}

// Round 2
// 72.625 us; speedup vs baseline: 1.0523x; 1.0523x over previous
//
#include <hip/hip_runtime.h>

#define NB 8
#define NP 16
#define NV 64
#define ND 1986

// output offsets in floats (concatenated return order)
#define OFF_POINTS 0         // (8,16*1986,3)    762624
#define OFF_DH     762624    // (8,16,1986,4)   1016832
#define OFF_OVER   1779456   // (8,16,1)            128
#define OFF_MEAN   1779584   // (8,16,3)            384
#define OFF_DIRS   1779968   // (1986,3)           5958
#define OFF_LOCALV 1785926   // (8,16,64,3)       24576
// total 1810502

// Block = (bp, 128-direction chunk); thread pair (lane, lane^1) shares one
// direction, each lane owns 32 of the 64 vertices -> zv[32] fits well under
// the 128-VGPR cap at 4 waves/SIMD (the zv[64] variant risked scratch spill).
// Max-normalization (zn = zm / max zm) replaces the reference's k-rescale:
// k cancels in every output, sum' >= 1 so all LB/UB clips are invisible
// (<=1e-19 absolute vs 0.129 threshold).
__global__ __launch_bounds__(256, 4) void mcx_kernel(
    const float* __restrict__ verts,    // (8,16,64,3)
    const float* __restrict__ smooth,   // (8,16)
    float* __restrict__ out)
{
    const int t     = threadIdx.x;
    const int bp    = blockIdx.x >> 4;   // 0..127
    const int chunk = blockIdx.x & 15;   // 0..15
    const int dl    = t >> 1;            // 0..127 direction within chunk
    const int half  = t & 1;             // which 32 vertices
    const int d     = chunk * 128 + dl;  // direction id (may exceed ND-1)

    __shared__ float lv[NV][4];          // padded float4 layout
    __shared__ float mean_sh[3];

    // ---- stage 1: load vertices, compute mean, local_v ----
    const int v3 = t / 3;
    const int c3 = t - v3 * 3;
    if (t < 192) lv[v3][c3] = verts[bp * 192 + t];
    else         lv[t - 192][3] = 0.f;
    __syncthreads();
    if (t < 3) {
        float s = 0.f;
        for (int v = 0; v < NV; ++v) s += lv[v][t];
        mean_sh[t] = s * (1.f / 64.f);
    }
    __syncthreads();
    const float m0 = mean_sh[0], m1 = mean_sh[1], m2 = mean_sh[2];
    if (t < 192) lv[v3][c3] -= mean_sh[c3];
    __syncthreads();

    if (chunk == 0) {
        if (t < 192) out[OFF_LOCALV + bp * 192 + t] = lv[v3][c3];
        if (t < 3)   out[OFF_MEAN + bp * 3 + t] = mean_sh[t];
        if (t == 3)  out[OFF_OVER + bp] = 0.f;
    }

    if (d >= ND) return;   // pair lanes share d -> partners exit together

    // ---- stage 2: direction vector ----
    int i, j;
    if (d < 1984) { i = 1 + (d >> 6); j = d & 63; }
    else          { i = (d == 1984) ? 0 : 32; j = 0; }
    const double STEP = 3.141592653589793 / 32.0;
    const float th1 = (float)(-1.5707963267948966 + (double)i * STEP);
    const float th2 = (float)(-3.141592653589793  + (double)j * STEP);
    const float c1 = cosf(th1), s1 = sinf(th1);
    const float c2 = cosf(th2), s2 = sinf(th2);
    const float dx = c1 * c2, dy = c1 * s2, dz = s1;
    if (bp == 0 && half == 0) {
        out[OFF_DIRS + d * 3 + 0] = dx;
        out[OFF_DIRS + d * 3 + 1] = dy;
        out[OFF_DIRS + d * 3 + 2] = dz;
    }

    // ---- stage 3: max-normalized p-norm support function ----
    const float sm  = smooth[bp];        // p (wave-uniform), in [2,20]
    const float ip  = 1.0f / sm;
    const float pm1 = sm - 1.0f;
    const int voff  = half * 32;

    // pass 1: z = <local_v, dir>, clamp at 0, track max
    float zv[32];
    float m = 0.f;
    #pragma unroll
    for (int v = 0; v < 32; ++v) {
        const float* q = lv[voff + v];
        float z = fmaf(q[0], dx, fmaf(q[1], dy, q[2] * dz));
        z = fmaxf(z, 0.f);
        zv[v] = z;
        m = fmaxf(m, z);
    }
    m = fmaxf(m, __shfl_xor(m, 1, 64));  // pair-combine: max over all 64 verts
    m = fmaxf(m, 1e-37f);                // guard (all-nonpositive never occurs)
    const float lm = __log2f(m);

    // pass 2: sum of (zm/m)^p in log2 space; cache lzn = log2(zm)-lm
    float sum = 0.f;
    #pragma unroll
    for (int v = 0; v < 32; ++v) {
        float lz = __log2f(zv[v]) - lm;  // zm==0 -> -inf (exp2 -> 0)
        zv[v] = lz;
        sum += exp2f(sm * lz);
    }
    sum += __shfl_xor(sum, 1, 64);       // pair-combine; sum >= 1 by construction
    const float lh = ip * __log2f(fmaxf(sum, 1e-30f));  // log2 of h' = sum^(1/p)

    // pass 3: dhdz = (zn/h')^(p-1) = exp2(pm1*(lzn-lh)); accumulate surf
    float sx = 0.f, sy = 0.f, sz = 0.f;
    #pragma unroll
    for (int v = 0; v < 32; ++v) {
        float dh = exp2f(pm1 * (zv[v] - lh));
        const float* q = lv[voff + v];
        sx = fmaf(dh, q[0], sx);
        sy = fmaf(dh, q[1], sy);
        sz = fmaf(dh, q[2], sz);
    }
    sx += __shfl_xor(sx, 1, 64);
    sy += __shfl_xor(sy, 1, 64);
    sz += __shfl_xor(sz, 1, 64);

    const float hout = m * exp2f(lh);    // h_out = m * h' (k cancels exactly)

    const int idx = bp * ND + d;
    if (half == 0) {
        out[OFF_POINTS + idx * 3 + 0] = sx + m0;
        out[OFF_POINTS + idx * 3 + 1] = sy + m1;
        out[OFF_POINTS + idx * 3 + 2] = sz + m2;
    } else {
        out[OFF_DH + idx * 4 + 0] = dx;
        out[OFF_DH + idx * 4 + 1] = dy;
        out[OFF_DH + idx * 4 + 2] = dz;
        out[OFF_DH + idx * 4 + 3] = hout;
    }
}

extern "C" void kernel_launch(void* const* d_in, const int* in_sizes, int n_in,
                              void* d_out, int out_size, void* d_ws, size_t ws_size,
                              hipStream_t stream) {
    const float* verts  = (const float*)d_in[0];   // (8,16,64,3) f32
    const float* smooth = (const float*)d_in[1];   // (8,16) f32
    float* out = (float*)d_out;
    (void)d_ws; (void)ws_size; (void)in_sizes; (void)n_in; (void)out_size;
    mcx_kernel<<<dim3(NB * NP * 16), dim3(256), 0, stream>>>(verts, smooth, out);
}

// Round 3
// 71.269 us; speedup vs baseline: 1.0724x; 1.0190x over previous
//
#include <hip/hip_runtime.h>

#define NB 8
#define NP 16
#define NV 64
#define ND 1986

// output offsets in floats (concatenated return order)
#define OFF_POINTS 0         // (8,16*1986,3)    762624
#define OFF_DH     762624    // (8,16,1986,4)   1016832  (16B-aligned: /4=190656)
#define OFF_OVER   1779456   // (8,16,1)            128
#define OFF_MEAN   1779584   // (8,16,3)            384
#define OFF_DIRS   1779968   // (1986,3)           5958
#define OFF_LOCALV 1785926   // (8,16,64,3)       24576
// total 1810502

__device__ __forceinline__ float fexp2(float x) { return __builtin_amdgcn_exp2f(x); }  // v_exp_f32
__device__ __forceinline__ float flog2(float x) { return __builtin_amdgcn_logf(x); }   // v_log_f32 (base 2)

// Structure: block = (bp, 256-direction chunk). Quad of lanes per direction,
// each lane owns 16 vertices IN REGISTERS (loaded from LDS once), and each
// quad processes 4 directions sequentially. This cuts LDS broadcast traffic
// ~8x vs the previous version (which re-read all vertices from LDS in pass 1
// AND pass 3 for every direction) -- that rebroadcast was the ~29us cost.
// zv[16] + 48 vertex regs keeps VGPR ~<110 under the 128 cap (4 waves/SIMD).
__global__ __launch_bounds__(256, 4) void mcx_kernel(
    const float* __restrict__ verts,    // (8,16,64,3)
    const float* __restrict__ smooth,   // (8,16)
    float* __restrict__ out)
{
    const int t     = threadIdx.x;
    const int bp    = blockIdx.x >> 3;   // 0..127
    const int chunk = blockIdx.x & 7;    // 0..7, 256 dirs each
    const int quad  = t >> 2;            // 0..63 direction slot
    const int lane4 = t & 3;             // which 16 vertices

    __shared__ float4 lv4[NV];
    __shared__ float  mean_sh[3];
    float* lvf = (float*)lv4;

    // ---- stage 1: load vertices, compute mean, local_v ----
    const int v3 = t / 3;
    const int c3 = t - v3 * 3;
    if (t < 192) lvf[v3 * 4 + c3] = verts[bp * 192 + t];
    else if (t < 256) lvf[(t - 192) * 4 + 3] = 0.f;
    __syncthreads();
    if (t < 3) {
        float s = 0.f;
        for (int v = 0; v < NV; ++v) s += lvf[v * 4 + t];
        mean_sh[t] = s * (1.f / 64.f);
    }
    __syncthreads();
    const float m0 = mean_sh[0], m1 = mean_sh[1], m2 = mean_sh[2];
    if (t < 192) lvf[v3 * 4 + c3] -= mean_sh[c3];
    __syncthreads();

    if (chunk == 0) {
        if (t < 192) out[OFF_LOCALV + bp * 192 + t] = lvf[v3 * 4 + c3];
        if (t < 3)   out[OFF_MEAN + bp * 3 + t] = mean_sh[t];
        if (t == 3)  out[OFF_OVER + bp] = 0.f;
    }

    // ---- one-time LDS -> register broadcast of this lane's 16 vertices ----
    float vxr[16], vyr[16], vzr[16];
    #pragma unroll
    for (int k = 0; k < 16; ++k) {
        float4 q = lv4[lane4 * 16 + k];
        vxr[k] = q.x; vyr[k] = q.y; vzr[k] = q.z;
    }

    const float sm  = smooth[bp];        // p, wave-uniform, in [2,20]
    const float ip  = 1.f / sm;
    const float pm1 = sm - 1.f;

    #pragma unroll 1                     // rolled: keeps zv[16] live once
    for (int g = 0; g < 4; ++g) {
        const int d = chunk * 256 + g * 64 + quad;
        if (d >= ND) continue;

        // direction vector (linspace step = pi/32 for both th1 and th2)
        int i, j;
        if (d < 1984) { i = 1 + (d >> 6); j = d & 63; }
        else          { i = (d == 1984) ? 0 : 32; j = 0; }
        const float th1 = (float)(-1.5707963267948966 + (double)i * 0.09817477042468103);
        const float th2 = (float)(-3.141592653589793  + (double)j * 0.09817477042468103);
        const float c1 = __cosf(th1), s1 = __sinf(th1);
        const float c2 = __cosf(th2), s2 = __sinf(th2);
        const float dx = c1 * c2, dy = c1 * s2, dz = s1;

        // pass 1: z = <local_v, dir>, clamp at 0, track max (regs only)
        float zv[16];
        float m = 0.f;
        #pragma unroll
        for (int k = 0; k < 16; ++k) {
            float z = fmaf(vxr[k], dx, fmaf(vyr[k], dy, vzr[k] * dz));
            z = fmaxf(z, 0.f);
            zv[k] = z;
            m = fmaxf(m, z);
        }
        m = fmaxf(m, __shfl_xor(m, 1, 64));
        m = fmaxf(m, __shfl_xor(m, 2, 64));
        m = fmaxf(m, 1e-37f);
        const float lm = flog2(m);

        // pass 2: sum (zm/m)^p = sum exp2(p*l - p*lm); cache l = log2(zm)
        const float nslm = -sm * lm;
        float sum = 0.f;
        #pragma unroll
        for (int k = 0; k < 16; ++k) {
            float l = flog2(zv[k]);          // zm==0 -> -inf -> exp2 -> 0
            zv[k] = l;
            sum += fexp2(fmaf(sm, l, nslm));
        }
        sum += __shfl_xor(sum, 1, 64);
        sum += __shfl_xor(sum, 2, 64);       // sum >= 1 by construction
        const float lh = ip * flog2(sum);    // log2 of h' = sum^(1/p)

        // pass 3: dhdz = exp2(pm1*(l - lm - lh)); accumulate surf
        const float cc = -pm1 * (lm + lh);
        float sx = 0.f, sy = 0.f, sz = 0.f;
        #pragma unroll
        for (int k = 0; k < 16; ++k) {
            float dh = fexp2(fmaf(pm1, zv[k], cc));
            sx = fmaf(dh, vxr[k], sx);
            sy = fmaf(dh, vyr[k], sy);
            sz = fmaf(dh, vzr[k], sz);
        }
        sx += __shfl_xor(sx, 1, 64); sx += __shfl_xor(sx, 2, 64);
        sy += __shfl_xor(sy, 1, 64); sy += __shfl_xor(sy, 2, 64);
        sz += __shfl_xor(sz, 1, 64); sz += __shfl_xor(sz, 2, 64);

        const int idx = bp * ND + d;
        if (lane4 == 0) {
            out[OFF_POINTS + idx * 3 + 0] = sx + m0;
            out[OFF_POINTS + idx * 3 + 1] = sy + m1;
            out[OFF_POINTS + idx * 3 + 2] = sz + m2;
        } else if (lane4 == 1) {
            const float hout = m * fexp2(lh);    // h_out = m*h' (k cancels)
            ((float4*)out)[(OFF_DH >> 2) + idx] = make_float4(dx, dy, dz, hout);
        } else if (lane4 == 2 && bp == 0) {
            out[OFF_DIRS + d * 3 + 0] = dx;
            out[OFF_DIRS + d * 3 + 1] = dy;
            out[OFF_DIRS + d * 3 + 2] = dz;
        }
    }
}

extern "C" void kernel_launch(void* const* d_in, const int* in_sizes, int n_in,
                              void* d_out, int out_size, void* d_ws, size_t ws_size,
                              hipStream_t stream) {
    const float* verts  = (const float*)d_in[0];   // (8,16,64,3) f32
    const float* smooth = (const float*)d_in[1];   // (8,16) f32
    float* out = (float*)d_out;
    (void)d_ws; (void)ws_size; (void)in_sizes; (void)n_in; (void)out_size;
    mcx_kernel<<<dim3(NB * NP * 8), dim3(256), 0, stream>>>(verts, smooth, out);
}

// Round 4
// 69.962 us; speedup vs baseline: 1.0924x; 1.0187x over previous
//
#include <hip/hip_runtime.h>

#define NB 8
#define NP 16
#define NV 64
#define ND 1986

// output offsets in floats (concatenated return order)
#define OFF_POINTS 0         // (8,16*1986,3)    762624
#define OFF_DH     762624    // (8,16,1986,4)   1016832  (16B-aligned: /4=190656)
#define OFF_OVER   1779456   // (8,16,1)            128
#define OFF_MEAN   1779584   // (8,16,3)            384
#define OFF_DIRS   1779968   // (1986,3)           5958
#define OFF_LOCALV 1785926   // (8,16,64,3)       24576
// total 1810502

__device__ __forceinline__ float fexp2(float x) { return __builtin_amdgcn_exp2f(x); }  // v_exp_f32
__device__ __forceinline__ float flog2(float x) { return __builtin_amdgcn_logf(x); }   // v_log_f32
__device__ __forceinline__ float frcp (float x) { return __builtin_amdgcn_rcpf(x); }   // v_rcp_f32

// Kernel is transcendental-issue bound; harness reset (256MiB poison fill,
// ~41us + restore dispatches) dominates dur_us with a ~66us floor.
// This version cuts trans/element 3 -> 2:
//   g = zn^(p-1) = exp2(pm1*(l-lm));  zn^p = g*zn (zn = zm*rcp(m));
//   dhdz = g * exp2(-pm1*lh)          (scalar per direction -> 1 mul/elem)
__global__ __launch_bounds__(256, 4) void mcx_kernel(
    const float* __restrict__ verts,    // (8,16,64,3)
    const float* __restrict__ smooth,   // (8,16)
    float* __restrict__ out)
{
    const int t     = threadIdx.x;
    const int bp    = blockIdx.x >> 3;   // 0..127
    const int chunk = blockIdx.x & 7;    // 0..7, 256 dirs each
    const int quad  = t >> 2;            // 0..63 direction slot
    const int lane4 = t & 3;             // which 16 vertices

    __shared__ float4 lv4[NV];
    __shared__ float  mean_sh[3];
    float* lvf = (float*)lv4;

    // ---- stage 1: load vertices, compute mean, local_v ----
    const int v3 = t / 3;
    const int c3 = t - v3 * 3;
    if (t < 192) lvf[v3 * 4 + c3] = verts[bp * 192 + t];
    else if (t < 256) lvf[(t - 192) * 4 + 3] = 0.f;
    __syncthreads();
    if (t < 3) {
        float s = 0.f;
        for (int v = 0; v < NV; ++v) s += lvf[v * 4 + t];
        mean_sh[t] = s * (1.f / 64.f);
    }
    __syncthreads();
    const float m0 = mean_sh[0], m1 = mean_sh[1], m2 = mean_sh[2];
    if (t < 192) lvf[v3 * 4 + c3] -= mean_sh[c3];
    __syncthreads();

    if (chunk == 0) {
        if (t < 192) out[OFF_LOCALV + bp * 192 + t] = lvf[v3 * 4 + c3];
        if (t < 3)   out[OFF_MEAN + bp * 3 + t] = mean_sh[t];
        if (t == 3)  out[OFF_OVER + bp] = 0.f;
    }

    // ---- one-time LDS -> register broadcast of this lane's 16 vertices ----
    float vxr[16], vyr[16], vzr[16];
    #pragma unroll
    for (int k = 0; k < 16; ++k) {
        float4 q = lv4[lane4 * 16 + k];
        vxr[k] = q.x; vyr[k] = q.y; vzr[k] = q.z;
    }

    const float sm  = smooth[bp];        // p, wave-uniform, in [2,20]
    const float ip  = 1.f / sm;
    const float pm1 = sm - 1.f;

    #pragma unroll 1                     // rolled: zv[16] live once
    for (int g4 = 0; g4 < 4; ++g4) {
        const int d = chunk * 256 + g4 * 64 + quad;
        if (d >= ND) continue;

        // direction vector (linspace step = pi/32 for both th1 and th2)
        int i, j;
        if (d < 1984) { i = 1 + (d >> 6); j = d & 63; }
        else          { i = (d == 1984) ? 0 : 32; j = 0; }
        const float th1 = (float)(-1.5707963267948966 + (double)i * 0.09817477042468103);
        const float th2 = (float)(-3.141592653589793  + (double)j * 0.09817477042468103);
        const float c1 = __cosf(th1), s1 = __sinf(th1);
        const float c2 = __cosf(th2), s2 = __sinf(th2);
        const float dx = c1 * c2, dy = c1 * s2, dz = s1;

        // pass 1: z = <local_v, dir>, clamp at 0, track max (regs only)
        float zv[16];
        float m = 0.f;
        #pragma unroll
        for (int k = 0; k < 16; ++k) {
            float z = fmaf(vxr[k], dx, fmaf(vyr[k], dy, vzr[k] * dz));
            z = fmaxf(z, 0.f);
            zv[k] = z;
            m = fmaxf(m, z);
        }
        m = fmaxf(m, __shfl_xor(m, 1, 64));
        m = fmaxf(m, __shfl_xor(m, 2, 64));
        m = fmaxf(m, 1e-37f);
        const float lm = flog2(m);
        const float rm = frcp(m);

        // pass 2: g = zn^(p-1) = exp2(pm1*(l-lm)); sum zn^p = sum g*zn
        const float npm1lm = -pm1 * lm;
        float sum = 0.f;
        #pragma unroll
        for (int k = 0; k < 16; ++k) {
            float zm = zv[k];
            float l  = flog2(zm);                 // zm==0 -> -inf
            float g  = fexp2(fmaf(pm1, l, npm1lm)); // zn^(p-1); 0 when zm==0
            zv[k] = g;
            sum = fmaf(g, zm * rm, sum);          // += zn^p
        }
        sum += __shfl_xor(sum, 1, 64);
        sum += __shfl_xor(sum, 2, 64);            // sum >= 1 by construction
        const float lh = ip * flog2(sum);         // log2 of h' = sum^(1/p)
        const float ds = fexp2(-pm1 * lh);        // h'^-(p-1), scalar per dir

        // pass 3: dhdz = g * ds; accumulate surf (1 mul + 3 fma per elem)
        float sx = 0.f, sy = 0.f, sz = 0.f;
        #pragma unroll
        for (int k = 0; k < 16; ++k) {
            float dh = zv[k] * ds;
            sx = fmaf(dh, vxr[k], sx);
            sy = fmaf(dh, vyr[k], sy);
            sz = fmaf(dh, vzr[k], sz);
        }
        sx += __shfl_xor(sx, 1, 64); sx += __shfl_xor(sx, 2, 64);
        sy += __shfl_xor(sy, 1, 64); sy += __shfl_xor(sy, 2, 64);
        sz += __shfl_xor(sz, 1, 64); sz += __shfl_xor(sz, 2, 64);

        const int idx = bp * ND + d;
        if (lane4 == 0) {
            out[OFF_POINTS + idx * 3 + 0] = sx + m0;
            out[OFF_POINTS + idx * 3 + 1] = sy + m1;
            out[OFF_POINTS + idx * 3 + 2] = sz + m2;
        } else if (lane4 == 1) {
            const float hout = m * fexp2(lh);     // h_out = m*h' (k cancels)
            ((float4*)out)[(OFF_DH >> 2) + idx] = make_float4(dx, dy, dz, hout);
        } else if (lane4 == 2 && bp == 0) {
            out[OFF_DIRS + d * 3 + 0] = dx;
            out[OFF_DIRS + d * 3 + 1] = dy;
            out[OFF_DIRS + d * 3 + 2] = dz;
        }
    }
}

extern "C" void kernel_launch(void* const* d_in, const int* in_sizes, int n_in,
                              void* d_out, int out_size, void* d_ws, size_t ws_size,
                              hipStream_t stream) {
    const float* verts  = (const float*)d_in[0];   // (8,16,64,3) f32
    const float* smooth = (const float*)d_in[1];   // (8,16) f32
    float* out = (float*)d_out;
    (void)d_ws; (void)ws_size; (void)in_sizes; (void)n_in; (void)out_size;
    mcx_kernel<<<dim3(NB * NP * 8), dim3(256), 0, stream>>>(verts, smooth, out);
}